// Round 1
// baseline (37.029 us; speedup 1.0000x reference)
//
#include <hip/hip_runtime.h>
#include <math.h>

namespace {
constexpr int Bn = 8192, Pn = 128, Dn = 128;
constexpr float MAXN = 1.0f - 1e-5f;                 // (1-PROJ_EPS)/sqrt(c)
constexpr float CLAMPV = 16.63553233343869f;         // log(2/eps32)
constexpr float SMOOTH = 50.0f;
}

// ---------------- per-p prep: projected bias, cx, bw, 1/a_norm, lambda_p*a_norm
__global__ void prep_p_kernel(const float* __restrict__ weight,
                              const float* __restrict__ bias,
                              float* __restrict__ bp,
                              float* __restrict__ pp) {
  const int p = blockIdx.x;
  const int lane = threadIdx.x;  // 0..63
  const float* br = bias + p * Dn;
  const float* wr = weight + p * Dn;
  float b0 = br[lane], b1 = br[lane + 64];
  float w0 = wr[lane], w1 = wr[lane + 64];
  double nb2 = (double)b0 * b0 + (double)b1 * b1;
#pragma unroll
  for (int off = 32; off; off >>= 1) nb2 += __shfl_xor(nb2, off);
  double norm = sqrt(nb2);
  if (norm < 1e-15) norm = 1e-15;
  double scl = (norm > (double)MAXN) ? (double)MAXN / norm : 1.0;
  float bp0 = (float)((double)b0 * scl);
  float bp1 = (float)((double)b1 * scl);
  bp[p * Dn + lane] = bp0;
  bp[p * Dn + lane + 64] = bp1;
  double p2 = nb2 * scl * scl;
  double cx = 1.0 - p2;                 // = coef_x = 1 - c*||p||^2
  double bwl = (double)bp0 * w0 + (double)bp1 * w1;
  double w2l = (double)w0 * w0 + (double)w1 * w1;
#pragma unroll
  for (int off = 32; off; off >>= 1) {
    bwl += __shfl_xor(bwl, off);
    w2l += __shfl_xor(w2l, off);
  }
  if (lane == 0) {
    double an = cx * sqrt(w2l);         // ||a|| = (1-p2)*||w||
    if (an < 1e-15) an = 1e-15;
    pp[p]          = (float)cx;
    pp[Pn + p]     = (float)bwl;        // <bias_proj, w>
    pp[2 * Pn + p] = (float)(1.0 / an);
    pp[3 * Pn + p] = (float)(2.0 / cx * an);  // lambda_p * a_norm
  }
}

// ---------------- per-b prep: x2 and 2/(1-x2), f64-accurate
__global__ void prep_x_kernel(const float* __restrict__ x, float* __restrict__ xb) {
  const int row = blockIdx.x * 4 + (threadIdx.x >> 6);
  const int lane = threadIdx.x & 63;
  const float* xr = x + row * Dn;
  float x0 = xr[lane], x1 = xr[lane + 64];
  double s = (double)x0 * x0 + (double)x1 * x1;
#pragma unroll
  for (int off = 32; off; off >>= 1) s += __shfl_xor(s, off);
  if (lane == 0) {
    xb[row] = (float)s;
    xb[Bn + row] = (float)(2.0 / (1.0 - s));
  }
}

// ---------------- main: dual-dot register-tiled GEMM + fused transcendental epilogue
__global__ __launch_bounds__(256)
void main_kernel(const float* __restrict__ x,
                 const float* __restrict__ weight,
                 const float* __restrict__ bp,
                 const float* __restrict__ pp,
                 const float* __restrict__ xb,
                 float* __restrict__ out) {
  __shared__ float xs[64][33];
  __shared__ float wsh[64][33];
  __shared__ float bsh[64][33];
  const int tx = threadIdx.x;  // 0..15, p-direction
  const int ty = threadIdx.y;  // 0..15, b-direction
  const int tid = ty * 16 + tx;
  const int b0 = blockIdx.x * 64;
  const int p0 = blockIdx.y * 64;

  float accw[4][4] = {};
  float accb[4][4] = {};

  for (int k0 = 0; k0 < Dn; k0 += 32) {
#pragma unroll
    for (int rep = 0; rep < 2; ++rep) {
      int t = tid + rep * 256;           // t in [0,512): 64 rows x 8 float4
      int row = t >> 3;
      int kq = (t & 7) * 4;
      float4 xv = *reinterpret_cast<const float4*>(x + (size_t)(b0 + row) * Dn + k0 + kq);
      xs[row][kq + 0] = xv.x; xs[row][kq + 1] = xv.y;
      xs[row][kq + 2] = xv.z; xs[row][kq + 3] = xv.w;
      float4 wv = *reinterpret_cast<const float4*>(weight + (size_t)(p0 + row) * Dn + k0 + kq);
      wsh[row][kq + 0] = wv.x; wsh[row][kq + 1] = wv.y;
      wsh[row][kq + 2] = wv.z; wsh[row][kq + 3] = wv.w;
      float4 bv = *reinterpret_cast<const float4*>(bp + (size_t)(p0 + row) * Dn + k0 + kq);
      bsh[row][kq + 0] = bv.x; bsh[row][kq + 1] = bv.y;
      bsh[row][kq + 2] = bv.z; bsh[row][kq + 3] = bv.w;
    }
    __syncthreads();
#pragma unroll
    for (int k = 0; k < 32; ++k) {
      float xv[4], wv[4], bv[4];
#pragma unroll
      for (int i = 0; i < 4; ++i) xv[i] = xs[ty * 4 + i][k];
#pragma unroll
      for (int j = 0; j < 4; ++j) { wv[j] = wsh[tx * 4 + j][k]; bv[j] = bsh[tx * 4 + j][k]; }
#pragma unroll
      for (int i = 0; i < 4; ++i)
#pragma unroll
        for (int j = 0; j < 4; ++j) {
          accw[i][j] = fmaf(xv[i], wv[j], accw[i][j]);
          accb[i][j] = fmaf(xv[i], bv[j], accb[i][j]);
        }
    }
    __syncthreads();
  }

  float cxj[4], bwj[4], iaj[4], soj[4], x2i[4], fbi[4];
#pragma unroll
  for (int j = 0; j < 4; ++j) {
    int p = p0 + tx * 4 + j;
    cxj[j] = pp[p]; bwj[j] = pp[Pn + p]; iaj[j] = pp[2 * Pn + p]; soj[j] = pp[3 * Pn + p];
  }
#pragma unroll
  for (int i = 0; i < 4; ++i) {
    int b = b0 + ty * 4 + i;
    x2i[i] = xb[b]; fbi[i] = xb[Bn + b];
  }

#pragma unroll
  for (int i = 0; i < 4; ++i) {
    int b = b0 + ty * 4 + i;
#pragma unroll
    for (int j = 0; j < 4; ++j) {
      int p = p0 + tx * 4 + j;
      float sb = accb[i][j];                     // <bias_proj, x>; dot = -sb
      float xw = accw[i][j];                     // <w, x>
      float coefp = 1.0f + x2i[i] - 2.0f * sb;   // 1 + 2c*dot + c*x2
      float X = cxj[j] * xw - coefp * bwj[j];    // suba*den/cx
      float arg = X * fbi[i] * iaj[j];           // 2X/((1-x2)*||a||), den cancels
      // smooth_clamp(arg, -C, C, 50) with stable softplus (matches jax logaddexp)
      float z1 = SMOOTH * (arg + CLAMPV);
      float z2 = SMOOTH * (arg - CLAMPV);
      float sp1 = fmaxf(z1, 0.0f) + log1pf(expf(-fabsf(z1)));
      float sp2 = fmaxf(z2, 0.0f) + log1pf(expf(-fabsf(z2)));
      float argc = -CLAMPV + (sp1 - sp2) * (1.0f / SMOOTH);
      out[(size_t)b * Pn + p] = soj[j] * asinhf(argc);
    }
  }
}

extern "C" void kernel_launch(void* const* d_in, const int* in_sizes, int n_in,
                              void* d_out, int out_size, void* d_ws, size_t ws_size,
                              hipStream_t stream) {
  const float* x = (const float*)d_in[0];
  const float* w = (const float*)d_in[1];
  const float* bias = (const float*)d_in[2];
  float* out = (float*)d_out;
  float* ws = (float*)d_ws;
  float* bp = ws;                 // [P][D] projected bias
  float* pp = bp + Pn * Dn;       // 4*P per-p params
  float* xb = pp + 4 * Pn;        // 2*B per-b params

  hipLaunchKernelGGL(prep_p_kernel, dim3(Pn), dim3(64), 0, stream, w, bias, bp, pp);
  hipLaunchKernelGGL(prep_x_kernel, dim3(Bn / 4), dim3(256), 0, stream, x, xb);
  hipLaunchKernelGGL(main_kernel, dim3(Bn / 64, Pn / 64), dim3(16, 16), 0, stream,
                     x, w, bp, pp, xb, out);
}